// Round 6
// baseline (433.404 us; speedup 1.0000x reference)
//
#include <hip/hip_runtime.h>

#define N_NODES 100000
#define N_GRAPHS 64
#define N_EDGES 600000
#define BN_EPS 1e-5f

// ===========================================================================
// CSR build: deg histogram -> scan -> cursor fill.
// ===========================================================================
__global__ void deg_hist_kernel(const int* __restrict__ dst,
                                int* __restrict__ deg, int n_edges) {
    int e = blockIdx.x * blockDim.x + threadIdx.x;
    if (e < n_edges) atomicAdd(&deg[dst[e]], 1);
}

__global__ void scan1_kernel(const int* __restrict__ deg, int* __restrict__ excl,
                             int* __restrict__ partials, int n) {
    __shared__ int s[1024];
    int i = blockIdx.x * 1024 + threadIdx.x;
    int v = (i < n) ? deg[i] : 0;
    s[threadIdx.x] = v;
    __syncthreads();
    for (int off = 1; off < 1024; off <<= 1) {
        int t = (threadIdx.x >= (unsigned)off) ? s[threadIdx.x - off] : 0;
        __syncthreads();
        s[threadIdx.x] += t;
        __syncthreads();
    }
    if (i < n) excl[i] = s[threadIdx.x] - v;
    if (threadIdx.x == 1023) partials[blockIdx.x] = s[1023];
}

__global__ void scan2_kernel(int* partials, int nb) {
    __shared__ int s[128];
    int t = threadIdx.x;
    int v = (t < nb) ? partials[t] : 0;
    s[t] = v;
    __syncthreads();
    for (int off = 1; off < 128; off <<= 1) {
        int u = (t >= off) ? s[t - off] : 0;
        __syncthreads();
        s[t] += u;
        __syncthreads();
    }
    if (t < nb) partials[t] = s[t] - v;
}

__global__ void scan3_kernel(int* __restrict__ rowptr, const int* __restrict__ partials,
                             int n, int total) {
    int i = blockIdx.x * blockDim.x + threadIdx.x;
    if (i < n) rowptr[i] += partials[i >> 10];
    else if (i == n) rowptr[n] = total;
}

__global__ void csr_fill_kernel(const int* __restrict__ src, const int* __restrict__ dst,
                                const int* __restrict__ rowptr, int* __restrict__ cursor,
                                int* __restrict__ eids, int n_edges) {
    int e = blockIdx.x * blockDim.x + threadIdx.x;
    if (e >= n_edges) return;
    int t = dst[e];
    int pos = rowptr[t] + atomicAdd(&cursor[t], 1);
    eids[pos] = src[e];
}

// ===========================================================================
// Graph boundaries from sorted batch.
// ===========================================================================
__global__ void graph_bounds_kernel(const int* __restrict__ batch,
                                    int* __restrict__ gstart, int n_nodes) {
    int n = blockIdx.x * blockDim.x + threadIdx.x;
    if (n >= n_nodes) return;
    if (n == 0) {
        for (int g = 0; g <= batch[0]; ++g) gstart[g] = 0;
    } else {
        int b0 = batch[n - 1], b1 = batch[n];
        for (int g = b0 + 1; g <= b1; ++g) gstart[g] = n;
    }
    if (n == n_nodes - 1) {
        for (int g = batch[n] + 1; g <= N_GRAPHS; ++g) gstart[g] = n_nodes;
    }
}

// ===========================================================================
// Prep per layer: w1T[j][k] = w1[k][j]; w2sT[c][j] = w2[j][c]*s[c];
// bias2[c] = (b2[c]-m[c])*s[c]+bb[c].
// ===========================================================================
__global__ void prep_kernel(const float* __restrict__ w1, const float* __restrict__ w2,
                            const float* __restrict__ b2, const float* __restrict__ g,
                            const float* __restrict__ bb, const float* __restrict__ m,
                            const float* __restrict__ v,
                            float* __restrict__ w1T, float* __restrict__ w2sT,
                            float* __restrict__ bias2, int DIN, int DOUT) {
    int i = blockIdx.x * blockDim.x + threadIdx.x;
    if (i < 64 * DIN) {
        int j = i / DIN, k = i % DIN;
        w1T[i] = w1[k * 64 + j];
    }
    int i2 = i - 64 * DIN;
    if (i2 >= 0 && i2 < DOUT * 64) {
        int c = i2 / 64, j = i2 % 64;
        float s = g[c] * rsqrtf(v[c] + BN_EPS);
        w2sT[i2] = w2[j * DOUT + c] * s;
    }
    int i3 = i2 - DOUT * 64;
    if (i3 >= 0 && i3 < DOUT) {
        float s = g[i3] * rsqrtf(v[i3] + BN_EPS);
        bias2[i3] = (b2[i3] - m[i3]) * s + bb[i3];
    }
}

// ===========================================================================
// pre-GEMM: y = x @ W1_0 (100k x 128 -> 100k x 64). A read straight from
// global (broadcast across the 16-lane jg group -> L1-served); only weights
// staged in LDS (32 KB -> ~5 blocks/CU).
// ===========================================================================
__global__ __launch_bounds__(256)
void pre_gemm_kernel(const float* __restrict__ x, const float* __restrict__ w1T,
                     float* __restrict__ y, int n_nodes) {
    __shared__ float w1s[64 * 128];
    const int tid = threadIdx.x;
    const long base = (long)blockIdx.x * 64;

    const float4* gw1 = (const float4*)w1T;
    for (int i4 = tid; i4 < 16 * 128; i4 += 256) {
        int row = i4 >> 5, k4 = i4 & 31;
        *(float4*)&w1s[row * 128 + ((k4 ^ ((row >> 2) & 7)) << 2)] = gw1[i4];
    }
    __syncthreads();

    const int jg = tid & 15, ng = tid >> 4, xw = jg & 7;
    const float* wp = &w1s[(jg * 4) * 128];
    const float4* xv = (const float4*)x;
    long r[4];
    #pragma unroll
    for (int i = 0; i < 4; ++i) {
        long rr = base + ng * 4 + i;
        r[i] = (rr < n_nodes) ? rr : (n_nodes - 1);  // clamp: x has no padding
    }
    float acc[4][4] = {};
    #pragma unroll 4
    for (int k4 = 0; k4 < 32; ++k4) {
        const int ko = (k4 ^ xw) << 2;
        float4 w0 = *(const float4*)&wp[0 * 128 + ko];
        float4 w1v = *(const float4*)&wp[1 * 128 + ko];
        float4 w2v = *(const float4*)&wp[2 * 128 + ko];
        float4 w3v = *(const float4*)&wp[3 * 128 + ko];
        #pragma unroll
        for (int i = 0; i < 4; ++i) {
            float4 a = xv[r[i] * 32 + k4];
            acc[i][0] = fmaf(a.x, w0.x, fmaf(a.y, w0.y, fmaf(a.z, w0.z, fmaf(a.w, w0.w, acc[i][0]))));
            acc[i][1] = fmaf(a.x, w1v.x, fmaf(a.y, w1v.y, fmaf(a.z, w1v.z, fmaf(a.w, w1v.w, acc[i][1]))));
            acc[i][2] = fmaf(a.x, w2v.x, fmaf(a.y, w2v.y, fmaf(a.z, w2v.z, fmaf(a.w, w2v.w, acc[i][2]))));
            acc[i][3] = fmaf(a.x, w3v.x, fmaf(a.y, w3v.y, fmaf(a.z, w3v.z, fmaf(a.w, w3v.w, acc[i][3]))));
        }
    }
    #pragma unroll
    for (int i = 0; i < 4; ++i) {
        long n = base + ng * 4 + i;
        if (n < n_nodes) {
            float4 v = {acc[i][0], acc[i][1], acc[i][2], acc[i][3]};
            *(float4*)(y + n * 64 + jg * 4) = v;
        }
    }
}

// ===========================================================================
// Gather (64-wide) + epilogue: t[n] = relu( y[n] + sum_{s in adj(n)} y[s] + b1 ).
// float4/lane, 16 lanes/node -> 4 node chains/wave; unroll x4.
// ===========================================================================
__global__ __launch_bounds__(256)
void gather64_kernel(const float* __restrict__ y, const int* __restrict__ rowptr,
                     const int* __restrict__ eids, const float* __restrict__ b1,
                     float* __restrict__ t, int n_nodes) {
    int node = blockIdx.x * 16 + (threadIdx.x >> 4);
    if (node >= n_nodes) return;
    int f4 = threadIdx.x & 15;
    const float4* yv = (const float4*)y;
    float4 acc = yv[(long)node * 16 + f4];
    int b = rowptr[node], e = rowptr[node + 1];
    int i = b;
    for (; i + 3 < e; i += 4) {
        int s0 = eids[i], s1 = eids[i + 1], s2 = eids[i + 2], s3 = eids[i + 3];
        float4 r0 = yv[(long)s0 * 16 + f4];
        float4 r1 = yv[(long)s1 * 16 + f4];
        float4 r2 = yv[(long)s2 * 16 + f4];
        float4 r3 = yv[(long)s3 * 16 + f4];
        acc.x += (r0.x + r1.x) + (r2.x + r3.x);
        acc.y += (r0.y + r1.y) + (r2.y + r3.y);
        acc.z += (r0.z + r1.z) + (r2.z + r3.z);
        acc.w += (r0.w + r1.w) + (r2.w + r3.w);
    }
    for (; i < e; ++i) {
        int s = eids[i];
        float4 r = yv[(long)s * 16 + f4];
        acc.x += r.x; acc.y += r.y; acc.z += r.z; acc.w += r.w;
    }
    float4 bv = ((const float4*)b1)[f4];
    float4 o;
    o.x = fmaxf(acc.x + bv.x, 0.0f);
    o.y = fmaxf(acc.y + bv.y, 0.0f);
    o.z = fmaxf(acc.z + bv.z, 0.0f);
    o.w = fmaxf(acc.w + bv.w, 0.0f);
    ((float4*)t)[(long)node * 16 + f4] = o;
}

// ===========================================================================
// Fused mid layer: h = relu(t@W2s + bias2); ynext = h @ W1_next.
// A read from global (broadcast); single LDS weight buffer reused across
// phases; h round-trips through sT. LDS = 17.4 + 16 KB -> 4 blocks/CU.
// ===========================================================================
__global__ __launch_bounds__(256)
void fused_mid_kernel(const float* __restrict__ t, const float* __restrict__ w2sT,
                      const float* __restrict__ bias2, const float* __restrict__ w1nT,
                      float* __restrict__ ynext, int n_nodes) {
    constexpr int SS = 68;
    __shared__ float sT[64 * SS];
    __shared__ float wbuf[64 * 64];
    const int tid = threadIdx.x;
    const long base = (long)blockIdx.x * 64;

    // stage w2s
    const float4* gw2 = (const float4*)w2sT;
    for (int i4 = tid; i4 < 16 * 64; i4 += 256) {
        int row = i4 >> 4, k4 = i4 & 15;
        *(float4*)&wbuf[row * 64 + ((k4 ^ ((row >> 2) & 7)) << 2)] = gw2[i4];
    }
    __syncthreads();

    const int jg = tid & 15, ng = tid >> 4, xw = jg & 7;
    const float4* tv = (const float4*)(t + base * 64);

    // phase 1: h = relu(t @ w2s + bias2)
    float h[4][4];
    {
        const float* wp = &wbuf[(jg * 4) * 64];
        float acc[4][4] = {};
        #pragma unroll 4
        for (int k4 = 0; k4 < 16; ++k4) {
            const int ko = (k4 ^ xw) << 2;
            float4 w0 = *(const float4*)&wp[0 * 64 + ko];
            float4 w1v = *(const float4*)&wp[1 * 64 + ko];
            float4 w2v = *(const float4*)&wp[2 * 64 + ko];
            float4 w3v = *(const float4*)&wp[3 * 64 + ko];
            #pragma unroll
            for (int i = 0; i < 4; ++i) {
                float4 a = tv[(ng * 4 + i) * 16 + k4];
                acc[i][0] = fmaf(a.x, w0.x, fmaf(a.y, w0.y, fmaf(a.z, w0.z, fmaf(a.w, w0.w, acc[i][0]))));
                acc[i][1] = fmaf(a.x, w1v.x, fmaf(a.y, w1v.y, fmaf(a.z, w1v.z, fmaf(a.w, w1v.w, acc[i][1]))));
                acc[i][2] = fmaf(a.x, w2v.x, fmaf(a.y, w2v.y, fmaf(a.z, w2v.z, fmaf(a.w, w2v.w, acc[i][2]))));
                acc[i][3] = fmaf(a.x, w3v.x, fmaf(a.y, w3v.y, fmaf(a.z, w3v.z, fmaf(a.w, w3v.w, acc[i][3]))));
            }
        }
        float4 bv = *(const float4*)&bias2[jg * 4];
        #pragma unroll
        for (int i = 0; i < 4; ++i) {
            h[i][0] = fmaxf(acc[i][0] + bv.x, 0.0f);
            h[i][1] = fmaxf(acc[i][1] + bv.y, 0.0f);
            h[i][2] = fmaxf(acc[i][2] + bv.z, 0.0f);
            h[i][3] = fmaxf(acc[i][3] + bv.w, 0.0f);
        }
    }
    __syncthreads();  // all phase-1 wbuf reads done

    // write h to sT; restage wbuf with w1n
    #pragma unroll
    for (int i = 0; i < 4; ++i) {
        float4 hv = {h[i][0], h[i][1], h[i][2], h[i][3]};
        *(float4*)&sT[(ng * 4 + i) * SS + jg * 4] = hv;
    }
    const float4* gw1n = (const float4*)w1nT;
    for (int i4 = tid; i4 < 16 * 64; i4 += 256) {
        int row = i4 >> 4, k4 = i4 & 15;
        *(float4*)&wbuf[row * 64 + ((k4 ^ ((row >> 2) & 7)) << 2)] = gw1n[i4];
    }
    __syncthreads();

    // phase 2: ynext = h @ w1n
    {
        const float* ap = &sT[(ng * 4) * SS];
        const float* wp = &wbuf[(jg * 4) * 64];
        float acc[4][4] = {};
        #pragma unroll 4
        for (int k4 = 0; k4 < 16; ++k4) {
            const int ko = (k4 ^ xw) << 2;
            float4 w0 = *(const float4*)&wp[0 * 64 + ko];
            float4 w1v = *(const float4*)&wp[1 * 64 + ko];
            float4 w2v = *(const float4*)&wp[2 * 64 + ko];
            float4 w3v = *(const float4*)&wp[3 * 64 + ko];
            #pragma unroll
            for (int i = 0; i < 4; ++i) {
                float4 a = *(const float4*)&ap[i * SS + k4 * 4];
                acc[i][0] = fmaf(a.x, w0.x, fmaf(a.y, w0.y, fmaf(a.z, w0.z, fmaf(a.w, w0.w, acc[i][0]))));
                acc[i][1] = fmaf(a.x, w1v.x, fmaf(a.y, w1v.y, fmaf(a.z, w1v.z, fmaf(a.w, w1v.w, acc[i][1]))));
                acc[i][2] = fmaf(a.x, w2v.x, fmaf(a.y, w2v.y, fmaf(a.z, w2v.z, fmaf(a.w, w2v.w, acc[i][2]))));
                acc[i][3] = fmaf(a.x, w3v.x, fmaf(a.y, w3v.y, fmaf(a.z, w3v.z, fmaf(a.w, w3v.w, acc[i][3]))));
            }
        }
        #pragma unroll
        for (int i = 0; i < 4; ++i) {
            long n = base + ng * 4 + i;
            if (n < n_nodes) {
                float4 v = {acc[i][0], acc[i][1], acc[i][2], acc[i][3]};
                *(float4*)(ynext + n * 64 + jg * 4) = v;
            }
        }
    }
}

// ===========================================================================
// Fused final layer: out = relu(t@W2s + bias2), 96-wide. A from global;
// LDS = 24 KB weights only -> 6 blocks/CU.
// ===========================================================================
__global__ __launch_bounds__(256)
void fused_final_kernel(const float* __restrict__ t, const float* __restrict__ w2sT,
                        const float* __restrict__ bias2, float* __restrict__ out,
                        int n_nodes) {
    constexpr int CPT = 6;
    __shared__ float w2s[96 * 64];
    const int tid = threadIdx.x;
    const long base = (long)blockIdx.x * 64;

    const float4* gw2 = (const float4*)w2sT;
    for (int i4 = tid; i4 < 96 * 16; i4 += 256) {
        int row = i4 >> 4, k4 = i4 & 15;
        *(float4*)&w2s[row * 64 + ((k4 ^ ((row / CPT) & 7)) << 2)] = gw2[i4];
    }
    __syncthreads();

    const int cg = tid & 15, ng = tid >> 4, xw = cg & 7;
    const float4* tv = (const float4*)(t + base * 64);
    const float* wp = &w2s[(cg * CPT) * 64];
    float acc[4][CPT] = {};
    #pragma unroll 4
    for (int k4 = 0; k4 < 16; ++k4) {
        const int ko = (k4 ^ xw) << 2;
        float4 wv[CPT];
        #pragma unroll
        for (int c = 0; c < CPT; ++c) wv[c] = *(const float4*)&wp[c * 64 + ko];
        #pragma unroll
        for (int i = 0; i < 4; ++i) {
            float4 h = tv[(ng * 4 + i) * 16 + k4];
            #pragma unroll
            for (int c = 0; c < CPT; ++c)
                acc[i][c] = fmaf(h.x, wv[c].x, fmaf(h.y, wv[c].y, fmaf(h.z, wv[c].z, fmaf(h.w, wv[c].w, acc[i][c]))));
        }
    }
    float bv[CPT];
    #pragma unroll
    for (int c = 0; c < CPT; ++c) bv[c] = bias2[cg * CPT + c];
    #pragma unroll
    for (int i = 0; i < 4; ++i) {
        long n = base + ng * 4 + i;
        if (n < n_nodes) {
            float* op = out + n * 96 + cg * CPT;
            #pragma unroll
            for (int c = 0; c < CPT; ++c) op[c] = fmaxf(acc[i][c] + bv[c], 0.0f);
        }
    }
}

// ===========================================================================
// Mean-pool over sorted batch via graph boundaries.
// ===========================================================================
#define POOL_SPLIT 16
__global__ __launch_bounds__(192)
void pool_seg_kernel(const float* __restrict__ h, const int* __restrict__ gstart,
                     float* __restrict__ sums) {
    int g = blockIdx.x >> 4;
    int s = blockIdx.x & 15;
    int lo = gstart[g], hi = gstart[g + 1];
    int len = hi - lo;
    int seg = (len + POOL_SPLIT - 1) / POOL_SPLIT;
    int a = lo + s * seg;
    int b = a + seg; if (b > hi) b = hi;

    int f4 = threadIdx.x % 24;
    int chain = threadIdx.x / 24;
    const float4* hv = (const float4*)h;
    float4 acc = {0.0f, 0.0f, 0.0f, 0.0f};
    for (int n = a + chain; n < b; n += 8) {
        float4 v = hv[(long)n * 24 + f4];
        acc.x += v.x; acc.y += v.y; acc.z += v.z; acc.w += v.w;
    }
    __shared__ float4 red[8][24];
    red[chain][f4] = acc;
    __syncthreads();
    if (threadIdx.x < 24) {
        float4 t = red[0][threadIdx.x];
        #pragma unroll
        for (int c = 1; c < 8; ++c) {
            float4 r = red[c][threadIdx.x];
            t.x += r.x; t.y += r.y; t.z += r.z; t.w += r.w;
        }
        float* sp = &sums[g * 96 + threadIdx.x * 4];
        atomicAdd(sp + 0, t.x);
        atomicAdd(sp + 1, t.y);
        atomicAdd(sp + 2, t.z);
        atomicAdd(sp + 3, t.w);
    }
}

__global__ void finalize_kernel(const float* __restrict__ sums,
                                const int* __restrict__ gstart,
                                float* __restrict__ out) {
    int i = blockIdx.x * blockDim.x + threadIdx.x;
    if (i >= N_GRAPHS * 96) return;
    int g = i / 96;
    float cnt = (float)(gstart[g + 1] - gstart[g]);
    out[i] = sums[i] / fmaxf(cnt, 1.0f);
}

// ---------------------------------------------------------------------------
static inline int cdiv_l(long a, int b) { return (int)((a + b - 1) / b); }

extern "C" void kernel_launch(void* const* d_in, const int* in_sizes, int n_in,
                              void* d_out, int out_size, void* d_ws, size_t ws_size,
                              hipStream_t stream) {
    const float* x     = (const float*)d_in[0];
    const int*   ei    = (const int*)d_in[1];
    const int*   src   = ei;
    const int*   dst   = ei + N_EDGES;
    const int*   batch = (const int*)d_in[2];

    const float* P[3][8];
    int p = 3;
    for (int l = 0; l < 3; ++l)
        for (int q = 0; q < 8; ++q)
            P[l][q] = (const float*)d_in[p++];

    const long NP = N_NODES + 64;
    float* ws   = (float*)d_ws;
    float* yT   = ws;               // NP*64  (linear-transformed features)
    float* gB   = yT + NP * 64;     // NP*64  (gathered t = relu(agg + b1))
    float* h2   = gB + NP * 64;     // NP*96  (final node features)
    float* q    = h2 + NP * 96;
    float* w1T[3], *w2sT[3], *bias2[3];
    for (int l = 0; l < 3; ++l) {
        w1T[l] = q;   q += 64 * 128;
        w2sT[l] = q;  q += 96 * 64;
        bias2[l] = q; q += 96;
    }
    float* sums   = q;
    int* gstart   = (int*)(sums + N_GRAPHS * 96);
    int* deg      = gstart + 72;
    int* cursor   = deg + N_NODES;
    int* partials = cursor + N_NODES;
    int* rowptr   = partials + 128;
    int* eids     = rowptr + (N_NODES + 1);

    const int B = 256;
    const int DIN[3]  = {128, 64, 64};
    const int DOUT[3] = {64, 64, 96};

    // ---- prep (independent of CSR) ----
    for (int l = 0; l < 3; ++l) {
        int tot = 64 * DIN[l] + 64 * DOUT[l] + DOUT[l];
        prep_kernel<<<cdiv_l(tot, B), B, 0, stream>>>(
            P[l][0], P[l][2], P[l][3], P[l][4], P[l][5], P[l][6], P[l][7],
            w1T[l], w2sT[l], bias2[l], DIN[l], DOUT[l]);
    }

    // ---- CSR build + graph bounds ----
    hipMemsetAsync(deg, 0, (size_t)(2 * N_NODES + 128) * sizeof(int), stream);
    deg_hist_kernel<<<cdiv_l(N_EDGES, B), B, 0, stream>>>(dst, deg, N_EDGES);
    int nblk = cdiv_l(N_NODES, 1024);
    scan1_kernel<<<nblk, 1024, 0, stream>>>(deg, rowptr, partials, N_NODES);
    scan2_kernel<<<1, 128, 0, stream>>>(partials, nblk);
    scan3_kernel<<<cdiv_l(N_NODES + 1, B), B, 0, stream>>>(rowptr, partials, N_NODES, N_EDGES);
    csr_fill_kernel<<<cdiv_l(N_EDGES, B), B, 0, stream>>>(src, dst, rowptr, cursor, eids, N_EDGES);
    graph_bounds_kernel<<<cdiv_l(N_NODES, B), B, 0, stream>>>(batch, gstart, N_NODES);

    const int ntiles = cdiv_l(N_NODES, 64);
    const int ngather = cdiv_l(N_NODES, 16);

    // ---- layer 0 ----
    pre_gemm_kernel<<<ntiles, 256, 0, stream>>>(x, w1T[0], yT, N_NODES);
    gather64_kernel<<<ngather, 256, 0, stream>>>(yT, rowptr, eids, P[0][1], gB, N_NODES);
    fused_mid_kernel<<<ntiles, 256, 0, stream>>>(
        gB, w2sT[0], bias2[0], w1T[1], yT, N_NODES);
    // ---- layer 1 ----
    gather64_kernel<<<ngather, 256, 0, stream>>>(yT, rowptr, eids, P[1][1], gB, N_NODES);
    fused_mid_kernel<<<ntiles, 256, 0, stream>>>(
        gB, w2sT[1], bias2[1], w1T[2], yT, N_NODES);
    // ---- layer 2 ----
    gather64_kernel<<<ngather, 256, 0, stream>>>(yT, rowptr, eids, P[2][1], gB, N_NODES);
    fused_final_kernel<<<ntiles, 256, 0, stream>>>(
        gB, w2sT[2], bias2[2], h2, N_NODES);

    // ---- global mean pool ----
    hipMemsetAsync(sums, 0, (size_t)(N_GRAPHS * 96) * sizeof(float), stream);
    pool_seg_kernel<<<N_GRAPHS * POOL_SPLIT, 192, 0, stream>>>(h2, gstart, sums);
    finalize_kernel<<<cdiv_l(N_GRAPHS * 96, B), B, 0, stream>>>(
        sums, gstart, (float*)d_out);
}